// Round 5
// baseline (257.090 us; speedup 1.0000x reference)
//
#include <hip/hip_runtime.h>
#include <hip/hip_bf16.h>
#include <cstdint>
#include <cstddef>

#define BATCH 4096
#define INC   1024
#define OUTC  1024
#define NB    8
#define KDIM  (INC * NB)   // 8192

// GEMM tile: 128x128 block, BK=64, 4 waves of 64x64 (4x4 frags of 16x16x32)
#define BM 128
#define BN 128
#define BK 64
#define SPLITS 8
#define KSPLIT (KDIM / SPLITS)   // 1024 -> 16 K-iters per block

typedef short  v8s __attribute__((ext_vector_type(8)));
typedef float  v4f __attribute__((ext_vector_type(4)));

__device__ __forceinline__ unsigned short f2bf(float f) {
  union { float f; unsigned u; } v; v.f = f;
  unsigned r = v.u + 0x7fffu + ((v.u >> 16) & 1u);  // round-to-nearest-even
  return (unsigned short)(r >> 16);
}
__device__ __forceinline__ float bf2f(unsigned short h) {
  union { unsigned u; float f; } v; v.u = ((unsigned)h) << 16; return v.f;
}

// async 16B global -> LDS (DMA; LDS dest = wave-uniform base + lane*16)
__device__ __forceinline__ void gld16(const unsigned short* g, unsigned short* l) {
  __builtin_amdgcn_global_load_lds(
      (const __attribute__((address_space(1))) unsigned int*)g,
      (__attribute__((address_space(3))) unsigned int*)l, 16, 0, 0);
}

// ---------------- Phase 1: expand basis -> bf16 A [BATCH][KDIM] ----------------
// basis_m = sigmoid(2*s*(u-c_m)) = 1/(1+exp2(a2*(c_m-u))); equispaced centers +
// uniform slope give e_m = e_0 * R^m (2 exp2 total).
__global__ __launch_bounds__(256) void expand_kernel(
    const float* __restrict__ x, const float* __restrict__ centers,
    const float* __restrict__ slopes, const float* __restrict__ alpha,
    const float* __restrict__ beta, unsigned short* __restrict__ Abf) {
  const int idx = blockIdx.x * 256 + threadIdx.x;   // (b,i) pair
  const int i = idx & (INC - 1);
  const float u = alpha[i] * x[idx] + beta[i];
  const float s0 = slopes[i * NB];
  const float c0 = centers[i * NB];
  const float c1 = centers[i * NB + 1];
  const float L2E2 = 2.8853900817779268f;   // 2*log2(e)
  const float a2 = L2E2 * s0;
  float e = __builtin_amdgcn_exp2f(a2 * (c0 - u));   // inf -> rcp -> 0 is the correct limit
  const float R = __builtin_amdgcn_exp2f(a2 * (c1 - c0));
  v8s outv;
#pragma unroll
  for (int m = 0; m < 8; ++m) {
    float basis = __builtin_amdgcn_rcpf(1.0f + e);
    outv[m] = (short)f2bf(basis);
    e *= R;
  }
  *(v8s*)(Abf + (size_t)idx * 8) = outv;    // 16B coalesced store
}

// ---------------- Phase 2: bf16 16x16x32 MFMA GEMM, split-K=8 -> bf16 partials ----------
// y[m,n] = sum_k A[m,k]*Bt[n,k].  A staged via global_load_lds (bf16 from ws); B read
// directly from fp32 coeffs, converted in-register, ds_write_b128 into LDS.
// LDS XOR swizzle: slot (row,kg) holds global k-group kg^(row&7); fragment reads use
// kgs = (kp*4+quad)^(row&7) -> 2-way max within 32-lane windows (free, R2-verified).
__global__ __launch_bounds__(256) void gemm_kernel(
    const unsigned short* __restrict__ A, const float* __restrict__ Bt32,
    unsigned short* __restrict__ partials) {
  __shared__ unsigned short As[BM * BK];   // 16 KiB
  __shared__ unsigned short Bs[BN * BK];   // 16 KiB

  // block decode: 256 blocks per z-plane; 8x8 supertiles consecutive
  const int id = blockIdx.x;
  const int z  = id >> 8;
  const int p  = id & 255;
  const int st = p >> 6;
  const int q  = p & 63;
  const int bx = q & 7;
  const int by = st * 8 + (q >> 3);
  const int bn0 = bx * BN;
  const int bm0 = by * BM;

  const int tid  = threadIdx.x;
  const int wave = tid >> 6;
  const int lane = tid & 63;
  const int quad = lane >> 4;
  const int lm   = lane & 15;
  const int wm = (wave & 1) * 64;
  const int wn = (wave >> 1) * 64;
  const int kt0 = z * KSPLIT;
  unsigned short* out = partials + (size_t)z * BATCH * OUTC;

  // staging decode: lane covers LDS slot (row = rb + (lane>>3), kgslot = lane&7);
  // fetches global k-group kg = kgslot ^ (r_in&7)   (rb multiple of 8)
  const int r_in = lane >> 3;
  const int kg   = (lane & 7) ^ r_in;        // r_in in 0..7 so &7 implicit

  const unsigned short* pA[4];
  const float* pB[4];
  unsigned short* lA[4];
  unsigned short* lB[4];
#pragma unroll
  for (int j = 0; j < 4; ++j) {
    const int rb = wave * 32 + j * 8;
    pA[j] = A    + (size_t)(bm0 + rb + r_in) * KDIM + kt0 + kg * 8;
    pB[j] = Bt32 + (size_t)(bn0 + rb + r_in) * KDIM + kt0 + kg * 8;
    lA[j] = As + rb * BK;                                   // DMA: base + lane*16
    lB[j] = Bs + (rb + r_in) * BK + (lane & 7) * 8;         // per-lane ds_write addr
  }

  v4f acc[4][4] = {};

  for (int it = 0; it < KSPLIT / BK; ++it) {
    // stage A via LDS-DMA, B via load-convert-write
#pragma unroll
    for (int j = 0; j < 4; ++j) {
      gld16(pA[j], lA[j]);
      float4 b0 = *(const float4*)(pB[j]);
      float4 b1 = *(const float4*)(pB[j] + 4);
      v8s bv;
      bv[0] = (short)f2bf(b0.x); bv[1] = (short)f2bf(b0.y);
      bv[2] = (short)f2bf(b0.z); bv[3] = (short)f2bf(b0.w);
      bv[4] = (short)f2bf(b1.x); bv[5] = (short)f2bf(b1.y);
      bv[6] = (short)f2bf(b1.z); bv[7] = (short)f2bf(b1.w);
      *(v8s*)lB[j] = bv;
      pA[j] += BK; pB[j] += BK;
    }
    __syncthreads();

#pragma unroll
    for (int kp = 0; kp < 2; ++kp) {
      v8s a[4], b[4];
#pragma unroll
      for (int fm = 0; fm < 4; ++fm) {
        const int row = wm + fm * 16 + lm;
        const int kgs = (kp * 4 + quad) ^ (row & 7);
        a[fm] = *(const v8s*)(As + row * BK + kgs * 8);
      }
#pragma unroll
      for (int fn = 0; fn < 4; ++fn) {
        const int row = wn + fn * 16 + lm;
        const int kgs = (kp * 4 + quad) ^ (row & 7);
        b[fn] = *(const v8s*)(Bs + row * BK + kgs * 8);
      }
#pragma unroll
      for (int fm = 0; fm < 4; ++fm)
#pragma unroll
        for (int fn = 0; fn < 4; ++fn)
          acc[fm][fn] = __builtin_amdgcn_mfma_f32_16x16x32_bf16(a[fm], b[fn], acc[fm][fn], 0, 0, 0);
    }
    __syncthreads();
  }

  // epilogue: C/D layout col = lane&15, row = quad*4 + reg; store bf16 partials
#pragma unroll
  for (int fm = 0; fm < 4; ++fm) {
    const int row0 = bm0 + wm + fm * 16 + quad * 4;
#pragma unroll
    for (int fn = 0; fn < 4; ++fn) {
      const int col = bn0 + wn + fn * 16 + lm;
#pragma unroll
      for (int r = 0; r < 4; ++r)
        out[(size_t)(row0 + r) * OUTC + col] = f2bf(acc[fm][fn][r]);
    }
  }
}

// ---------------- Phase 3: split-K reduction (bf16 partials -> fp32 out) ----------------
__global__ __launch_bounds__(256) void reduce_kernel(
    const unsigned short* __restrict__ P, float* __restrict__ out) {
  const size_t nel = (size_t)BATCH * OUTC;
  const size_t base = ((size_t)blockIdx.x * 256 + threadIdx.x) * 8;
  float s[8] = {};
#pragma unroll
  for (int t = 0; t < SPLITS; ++t) {
    v8s v = *(const v8s*)(P + t * nel + base);
#pragma unroll
    for (int j = 0; j < 8; ++j) s[j] += bf2f((unsigned short)v[j]);
  }
  float4 o0 = {s[0], s[1], s[2], s[3]};
  float4 o1 = {s[4], s[5], s[6], s[7]};
  *(float4*)(out + base) = o0;
  *(float4*)(out + base + 4) = o1;
}

extern "C" void kernel_launch(void* const* d_in, const int* in_sizes, int n_in,
                              void* d_out, int out_size, void* d_ws, size_t ws_size,
                              hipStream_t stream) {
  const float* x       = (const float*)d_in[0];
  const float* coeffs  = (const float*)d_in[1];
  const float* centers = (const float*)d_in[2];
  const float* slopes  = (const float*)d_in[3];
  const float* alpha   = (const float*)d_in[4];
  const float* beta    = (const float*)d_in[5];
  float* out = (float*)d_out;

  const size_t a_elems = (size_t)BATCH * KDIM;                 // 64 MiB bf16
  const size_t part_elems = (size_t)SPLITS * BATCH * OUTC;     // 67 MiB bf16
  if (ws_size < (a_elems + part_elems) * sizeof(unsigned short)) return;

  unsigned short* Abf = (unsigned short*)d_ws;
  unsigned short* partials = Abf + a_elems;

  expand_kernel<<<(BATCH * INC) / 256, 256, 0, stream>>>(
      x, centers, slopes, alpha, beta, Abf);

  gemm_kernel<<<(OUTC / BN) * (BATCH / BM) * SPLITS, 256, 0, stream>>>(
      Abf, coeffs, partials);

  reduce_kernel<<<(int)((size_t)BATCH * OUTC / 8 / 256), 256, 0, stream>>>(
      partials, out);
}

// Round 6
// 186.771 us; speedup vs baseline: 1.3765x; 1.3765x over previous
//
#include <hip/hip_runtime.h>
#include <hip/hip_bf16.h>
#include <cstdint>
#include <cstddef>

#define BATCH 4096
#define INC   1024
#define OUTC  1024
#define NB    8
#define KDIM  (INC * NB)   // 8192 (elements == bytes in i8)

// GEMM tile: 128x128 block, BK=128 i8, 4 waves of 64x64 (4x4 frags of 16x16x64 i8)
#define BM 128
#define BN 128
#define BKB 128            // k-bytes per iter
#define SPLITS 4
#define KSPLIT (KDIM / SPLITS)   // 2048 -> 16 K-iters per block

typedef int  v4i __attribute__((ext_vector_type(4)));
typedef char v8c __attribute__((ext_vector_type(8)));

// async 16B global -> LDS (DMA; LDS dest = wave-uniform base + lane*16)
__device__ __forceinline__ void gld16(const char* g, char* l) {
  __builtin_amdgcn_global_load_lds(
      (const __attribute__((address_space(1))) unsigned int*)g,
      (__attribute__((address_space(3))) unsigned int*)l, 16, 0, 0);
}

// ---------------- Phase 1: expand basis -> i8 A [BATCH][KDIM] ----------------
// basis_m = sigmoid(2*s*(u-c_m)); equispaced centers + uniform slope -> e_m = e0*R^m.
// Affine quant: qa = rint(basis*254 - 127) in [-127,127]; basis_hat = (qa+127)/254.
__global__ __launch_bounds__(256) void expand_kernel(
    const float* __restrict__ x, const float* __restrict__ centers,
    const float* __restrict__ slopes, const float* __restrict__ alpha,
    const float* __restrict__ beta, char* __restrict__ Ai8) {
  const int idx = blockIdx.x * 256 + threadIdx.x;   // (b,i) pair
  const int i = idx & (INC - 1);
  const float u = alpha[i] * x[idx] + beta[i];
  const float s0 = slopes[i * NB];
  const float c0 = centers[i * NB];
  const float c1 = centers[i * NB + 1];
  const float L2E2 = 2.8853900817779268f;   // 2*log2(e)
  const float a2 = L2E2 * s0;
  float e = __builtin_amdgcn_exp2f(a2 * (c0 - u));   // inf -> rcp -> 0 is the correct limit
  const float R = __builtin_amdgcn_exp2f(a2 * (c1 - c0));
  v8c q;
#pragma unroll
  for (int m = 0; m < 8; ++m) {
    float basis = __builtin_amdgcn_rcpf(1.0f + e);
    q[m] = (char)(int)rintf(basis * 254.0f - 127.0f);
    e *= R;
  }
  *(v8c*)(Ai8 + (size_t)idx * 8) = q;   // 8B coalesced store
}

// ---------------- Phase 2a: per-row coeff absmax ----------------
__global__ __launch_bounds__(256) void rowstat_kernel(
    const float4* __restrict__ coeffs4, float* __restrict__ maxrow) {
  const int o = blockIdx.x;
  const int tid = threadIdx.x;
  const float4* row = coeffs4 + (size_t)o * (KDIM / 4);
  float m = 0.0f;
  for (int t = tid; t < KDIM / 4; t += 256) {
    float4 v = row[t];
    m = fmaxf(m, fmaxf(fmaxf(fabsf(v.x), fabsf(v.y)), fmaxf(fabsf(v.z), fabsf(v.w))));
  }
#pragma unroll
  for (int off = 32; off; off >>= 1) m = fmaxf(m, __shfl_xor(m, off));
  __shared__ float wm[4];
  if ((tid & 63) == 0) wm[tid >> 6] = m;
  __syncthreads();
  if (tid == 0)
    maxrow[o] = fmaxf(fmaxf(fmaxf(wm[0], wm[1]), fmaxf(wm[2], wm[3])), 1e-30f);
}

// ---------------- Phase 2b: quantize coeffs -> i8, accumulate Sum(qc) per row --------
// qc = rint(c * 127/maxrow[o]); qcsum[o] += Sum qc (int, exact; zeroed via memsetAsync)
__global__ __launch_bounds__(256) void convert_kernel(
    const float4* __restrict__ coeffs4, const float* __restrict__ maxrow,
    int* __restrict__ Ci8_as_int, int* __restrict__ qcsum) {
  const int idx4 = blockIdx.x * 256 + threadIdx.x;
  const int o = idx4 >> 11;                 // 2048 float4 per row
  const float s = 127.0f / maxrow[o];       // block-uniform scalar
  float4 v = coeffs4[idx4];
  int q0 = (int)rintf(v.x * s), q1 = (int)rintf(v.y * s);
  int q2 = (int)rintf(v.z * s), q3 = (int)rintf(v.w * s);
  Ci8_as_int[idx4] = (q0 & 0xFF) | ((q1 & 0xFF) << 8) | ((q2 & 0xFF) << 16) | (q3 << 24);
  int qs = q0 + q1 + q2 + q3;
#pragma unroll
  for (int off = 32; off; off >>= 1) qs += __shfl_xor(qs, off);
  __shared__ int ws4[4];
  const int tid = threadIdx.x;
  if ((tid & 63) == 0) ws4[tid >> 6] = qs;
  __syncthreads();
  if (tid == 0) atomicAdd(&qcsum[o], ws4[0] + ws4[1] + ws4[2] + ws4[3]);
}

// ---------------- Phase 3: i8 16x16x64 MFMA GEMM, split-K=4 -> int32 partials -----------
// y_dot[m,n] = sum_k qa[m,k]*qc[n,k].  LDS XOR-swizzled in 16B k-groups: slot (row,g)
// holds global group g^(row&7); fragment reads kgs=(kp*4+quad)^(row&7) -> <=2-way (free).
// Same geometry as the verified bf16 kernel (8 groups of 16B per 128B row).
__global__ __launch_bounds__(256) void gemm_kernel(
    const char* __restrict__ A, const char* __restrict__ C,
    int* __restrict__ partials) {
  __shared__ char As[BM * BKB];   // 16 KiB
  __shared__ char Bs[BN * BKB];   // 16 KiB

  // block decode: 256 blocks per z-plane; 8x8 supertiles consecutive
  const int id = blockIdx.x;
  const int z  = id >> 8;
  const int p  = id & 255;
  const int st = p >> 6;
  const int q  = p & 63;
  const int bx = q & 7;
  const int by = st * 8 + (q >> 3);
  const int bn0 = bx * BN;
  const int bm0 = by * BM;

  const int tid  = threadIdx.x;
  const int wave = tid >> 6;
  const int lane = tid & 63;
  const int quad = lane >> 4;
  const int lm   = lane & 15;
  const int wm = (wave & 1) * 64;
  const int wn = (wave >> 1) * 64;
  const int kt0 = z * KSPLIT;
  int* out = partials + (size_t)z * BATCH * OUTC;

  // staging decode: lane covers LDS slot (row = rb + (lane>>3), group lane&7);
  // fetches global 16B-group kg = (lane&7) ^ row
  const int r_in = lane >> 3;
  const int kg   = (lane & 7) ^ r_in;

  const char* pA[4];
  const char* pB[4];
  char* lA[4];
  char* lB[4];
#pragma unroll
  for (int j = 0; j < 4; ++j) {
    const int rb = wave * 32 + j * 8;
    pA[j] = A + (size_t)(bm0 + rb + r_in) * KDIM + kt0 + kg * 16;
    pB[j] = C + (size_t)(bn0 + rb + r_in) * KDIM + kt0 + kg * 16;
    lA[j] = As + rb * BKB;
    lB[j] = Bs + rb * BKB;
  }

  v4i acc[4][4] = {};

  for (int it = 0; it < KSPLIT / BKB; ++it) {
#pragma unroll
    for (int j = 0; j < 4; ++j) {
      gld16(pA[j], lA[j]);
      gld16(pB[j], lB[j]);
      pA[j] += BKB; pB[j] += BKB;
    }
    __syncthreads();

#pragma unroll
    for (int kp = 0; kp < 2; ++kp) {
      v4i a[4], b[4];
#pragma unroll
      for (int fm = 0; fm < 4; ++fm) {
        const int row = wm + fm * 16 + lm;
        const int kgs = (kp * 4 + quad) ^ (row & 7);
        a[fm] = *(const v4i*)(As + row * BKB + kgs * 16);
      }
#pragma unroll
      for (int fn = 0; fn < 4; ++fn) {
        const int row = wn + fn * 16 + lm;
        const int kgs = (kp * 4 + quad) ^ (row & 7);
        b[fn] = *(const v4i*)(Bs + row * BKB + kgs * 16);
      }
#pragma unroll
      for (int fm = 0; fm < 4; ++fm)
#pragma unroll
        for (int fn = 0; fn < 4; ++fn)
          acc[fm][fn] = __builtin_amdgcn_mfma_i32_16x16x64_i8(a[fm], b[fn], acc[fm][fn], 0, 0, 0);
    }
    __syncthreads();
  }

  // epilogue: C/D layout (dtype-independent): col = lane&15, row = quad*4 + reg
#pragma unroll
  for (int fm = 0; fm < 4; ++fm) {
    const int row0 = bm0 + wm + fm * 16 + quad * 4;
#pragma unroll
    for (int fn = 0; fn < 4; ++fn) {
      const int col = bn0 + wn + fn * 16 + lm;
#pragma unroll
      for (int r = 0; r < 4; ++r)
        out[(size_t)(row0 + r) * OUTC + col] = acc[fm][fn][r];
    }
  }
}

// ---------------- Phase 4: reduce + dequant ----------------
// y[b,o] = M[o]/(127*254) * Sdot + M[o]/254 * Sum(qc[o])  =  M[o]*(Sdot + 127*Qc[o])/32258
__global__ __launch_bounds__(256) void reduce_kernel(
    const int4* __restrict__ P, const float4* __restrict__ maxrow4,
    const int4* __restrict__ qcsum4, float4* __restrict__ out) {
  const size_t n4 = (size_t)BATCH * OUTC / 4;
  const size_t idx4 = (size_t)blockIdx.x * 256 + threadIdx.x;
  int4 s = P[idx4];
#pragma unroll
  for (int t = 1; t < SPLITS; ++t) {
    int4 v = P[(size_t)t * n4 + idx4];
    s.x += v.x; s.y += v.y; s.z += v.z; s.w += v.w;
  }
  const int o4 = (int)(idx4 & (OUTC / 4 - 1));
  float4 M = maxrow4[o4];
  int4  Q = qcsum4[o4];
  const float inv = 1.0f / 32258.0f;   // 127*254
  float4 y;
  y.x = M.x * (float)(s.x + 127 * Q.x) * inv;
  y.y = M.y * (float)(s.y + 127 * Q.y) * inv;
  y.z = M.z * (float)(s.z + 127 * Q.z) * inv;
  y.w = M.w * (float)(s.w + 127 * Q.w) * inv;
  out[idx4] = y;
}

extern "C" void kernel_launch(void* const* d_in, const int* in_sizes, int n_in,
                              void* d_out, int out_size, void* d_ws, size_t ws_size,
                              hipStream_t stream) {
  const float* x       = (const float*)d_in[0];
  const float* coeffs  = (const float*)d_in[1];
  const float* centers = (const float*)d_in[2];
  const float* slopes  = (const float*)d_in[3];
  const float* alpha   = (const float*)d_in[4];
  const float* beta    = (const float*)d_in[5];
  float* out = (float*)d_out;

  const size_t a_bytes = (size_t)BATCH * KDIM;                 // 32 MiB i8
  const size_t c_bytes = (size_t)OUTC * KDIM;                  // 8 MiB i8
  const size_t stat_bytes = OUTC * sizeof(float);              // 4 KiB
  const size_t qcs_bytes  = OUTC * sizeof(int);                // 4 KiB
  const size_t part_bytes = (size_t)SPLITS * BATCH * OUTC * sizeof(int);  // 67 MiB
  if (ws_size < a_bytes + c_bytes + stat_bytes + qcs_bytes + part_bytes) return;

  char*  Ai8    = (char*)d_ws;
  char*  Ci8    = Ai8 + a_bytes;
  float* maxrow = (float*)(Ci8 + c_bytes);
  int*   qcsum  = (int*)((char*)maxrow + stat_bytes);
  int*   parts  = (int*)((char*)qcsum + qcs_bytes);

  expand_kernel<<<(BATCH * INC) / 256, 256, 0, stream>>>(
      x, centers, slopes, alpha, beta, Ai8);

  rowstat_kernel<<<OUTC, 256, 0, stream>>>((const float4*)coeffs, maxrow);

  hipMemsetAsync(qcsum, 0, qcs_bytes, stream);

  convert_kernel<<<(OUTC * KDIM / 4) / 256, 256, 0, stream>>>(
      (const float4*)coeffs, maxrow, (int*)Ci8, qcsum);

  gemm_kernel<<<(OUTC / BN) * (BATCH / BM) * SPLITS, 256, 0, stream>>>(
      Ai8, Ci8, parts);

  reduce_kernel<<<(int)((size_t)BATCH * OUTC / 4 / 256), 256, 0, stream>>>(
      (const int4*)parts, (const float4*)maxrow, (const int4*)qcsum, (float4*)out);
}

// Round 7
// 164.679 us; speedup vs baseline: 1.5612x; 1.1342x over previous
//
#include <hip/hip_runtime.h>
#include <hip/hip_bf16.h>
#include <cstdint>
#include <cstddef>

#define BATCH 4096
#define INC   1024
#define OUTC  1024
#define NB    8
#define KDIM  (INC * NB)   // 8192 (elements == bytes in i8)

// GEMM tile: 128x128 block, BK=128 i8, 4 waves of 64x64 (4x4 frags of 16x16x64 i8)
#define BM 128
#define BN 128
#define BKB 128            // k-bytes per iter
#define SPLITS 4
#define KSPLIT (KDIM / SPLITS)   // 2048 -> 16 K-iters per block

// prep dispatch partition: expand | fused rowmax+quant (one block per coeff row)
#define EXPAND_BLOCKS  ((BATCH * INC) / 256)   // 16384
#define QUANT_BLOCKS   OUTC                    // 1024
#define PREP_BLOCKS    (EXPAND_BLOCKS + QUANT_BLOCKS)

typedef int   v4i __attribute__((ext_vector_type(4)));
typedef char  v8c __attribute__((ext_vector_type(8)));
typedef short v8s __attribute__((ext_vector_type(8)));

__device__ __forceinline__ unsigned short f2bf(float f) {
  union { float f; unsigned u; } v; v.f = f;
  unsigned r = v.u + 0x7fffu + ((v.u >> 16) & 1u);  // round-to-nearest-even
  return (unsigned short)(r >> 16);
}
__device__ __forceinline__ float bf2f(unsigned short h) {
  union { unsigned u; float f; } v; v.u = ((unsigned)h) << 16; return v.f;
}

// async 16B global -> LDS (DMA; LDS dest = wave-uniform base + lane*16)
__device__ __forceinline__ void gld16(const char* g, char* l) {
  __builtin_amdgcn_global_load_lds(
      (const __attribute__((address_space(1))) unsigned int*)g,
      (__attribute__((address_space(3))) unsigned int*)l, 16, 0, 0);
}

// ---------------- Phase 1 (fused dispatch): expand basis | rowmax+quantize coeffs -------
// expand: basis_m = sigmoid(2*s*(u-c_m)); equispaced centers + uniform slope ->
//   e_m = e0*R^m (2 exp2 total). Affine quant qa = rint(basis*254-127).
// quant: one block per coeff row; row (32KB) held in registers across max-reduce,
//   then quantized: qc = rint(c*127/M). qcsum computed in-block (no atomics/memset).
__global__ __launch_bounds__(256) void prep_kernel(
    const float* __restrict__ x, const float4* __restrict__ coeffs4,
    const float* __restrict__ centers, const float* __restrict__ slopes,
    const float* __restrict__ alpha, const float* __restrict__ beta,
    char* __restrict__ Ai8, int* __restrict__ Ci8i,
    float* __restrict__ maxrow, int* __restrict__ qcsum) {
  const int blk = blockIdx.x;
  const int tid = threadIdx.x;
  if (blk < EXPAND_BLOCKS) {
    const int idx = blk * 256 + tid;          // (b,i) pair
    const int i = idx & (INC - 1);
    const float u = alpha[i] * x[idx] + beta[i];
    const float s0 = slopes[i * NB];
    const float c0 = centers[i * NB];
    const float c1 = centers[i * NB + 1];
    const float L2E2 = 2.8853900817779268f;   // 2*log2(e)
    const float a2 = L2E2 * s0;
    float e = __builtin_amdgcn_exp2f(a2 * (c0 - u));   // inf -> rcp -> 0: correct limit
    const float R = __builtin_amdgcn_exp2f(a2 * (c1 - c0));
    v8c q;
#pragma unroll
    for (int m = 0; m < 8; ++m) {
      float basis = __builtin_amdgcn_rcpf(1.0f + e);
      q[m] = (char)(int)rintf(basis * 254.0f - 127.0f);
      e *= R;
    }
    *(v8c*)(Ai8 + (size_t)idx * 8) = q;   // 8B coalesced store
  } else {
    const int o = blk - EXPAND_BLOCKS;
    const float4* row = coeffs4 + (size_t)o * (KDIM / 4);
    float4 v[8];
    float m = 0.0f;
#pragma unroll
    for (int j = 0; j < 8; ++j) {
      v[j] = row[tid + 256 * j];
      m = fmaxf(m, fmaxf(fmaxf(fabsf(v[j].x), fabsf(v[j].y)),
                         fmaxf(fabsf(v[j].z), fabsf(v[j].w))));
    }
#pragma unroll
    for (int off = 32; off; off >>= 1) m = fmaxf(m, __shfl_xor(m, off));
    __shared__ float wm[4];
    __shared__ int   wq[4];
    if ((tid & 63) == 0) wm[tid >> 6] = m;
    __syncthreads();
    const float M = fmaxf(fmaxf(fmaxf(wm[0], wm[1]), fmaxf(wm[2], wm[3])), 1e-30f);
    const float s = 127.0f / M;
    int qs = 0;
#pragma unroll
    for (int j = 0; j < 8; ++j) {
      int q0 = (int)rintf(v[j].x * s), q1 = (int)rintf(v[j].y * s);
      int q2 = (int)rintf(v[j].z * s), q3 = (int)rintf(v[j].w * s);
      Ci8i[(size_t)o * (KDIM / 4) + tid + 256 * j] =
          (q0 & 0xFF) | ((q1 & 0xFF) << 8) | ((q2 & 0xFF) << 16) | ((q3 & 0xFF) << 24);
      qs += q0 + q1 + q2 + q3;
    }
#pragma unroll
    for (int off = 32; off; off >>= 1) qs += __shfl_xor(qs, off);
    if ((tid & 63) == 0) wq[tid >> 6] = qs;
    __syncthreads();
    if (tid == 0) { maxrow[o] = M; qcsum[o] = wq[0] + wq[1] + wq[2] + wq[3]; }
  }
}

// ---------------- Phase 2: i8 16x16x64 MFMA GEMM, split-K=4 -> bf16 partials ------------
// y_dot[m,n] = sum_k qa[m,k]*qc[n,k].  LDS XOR-swizzled in 16B k-groups: slot (row,g)
// holds global group g^(row&7); fragment reads kgs=(kp*4+quad)^(row&7) -> <=2-way (free).
// Partials stored bf16 (rel err 2^-9 on ~1e5-magnitude dots -> ~6e-4 output err).
__global__ __launch_bounds__(256) void gemm_kernel(
    const char* __restrict__ A, const char* __restrict__ C,
    unsigned short* __restrict__ partials) {
  __shared__ char As[BM * BKB];   // 16 KiB
  __shared__ char Bs[BN * BKB];   // 16 KiB

  // block decode: 256 blocks per z-plane; 8x8 supertiles consecutive
  const int id = blockIdx.x;
  const int z  = id >> 8;
  const int p  = id & 255;
  const int st = p >> 6;
  const int q  = p & 63;
  const int bx = q & 7;
  const int by = st * 8 + (q >> 3);
  const int bn0 = bx * BN;
  const int bm0 = by * BM;

  const int tid  = threadIdx.x;
  const int wave = tid >> 6;
  const int lane = tid & 63;
  const int quad = lane >> 4;
  const int lm   = lane & 15;
  const int wm = (wave & 1) * 64;
  const int wn = (wave >> 1) * 64;
  const int kt0 = z * KSPLIT;
  unsigned short* out = partials + (size_t)z * BATCH * OUTC;

  // staging decode: lane covers LDS slot (row = rb + (lane>>3), group lane&7);
  // fetches global 16B-group kg = (lane&7) ^ row
  const int r_in = lane >> 3;
  const int kg   = (lane & 7) ^ r_in;

  const char* pA[4];
  const char* pB[4];
  char* lA[4];
  char* lB[4];
#pragma unroll
  for (int j = 0; j < 4; ++j) {
    const int rb = wave * 32 + j * 8;
    pA[j] = A + (size_t)(bm0 + rb + r_in) * KDIM + kt0 + kg * 16;
    pB[j] = C + (size_t)(bn0 + rb + r_in) * KDIM + kt0 + kg * 16;
    lA[j] = As + rb * BKB;
    lB[j] = Bs + rb * BKB;
  }

  v4i acc[4][4] = {};

  for (int it = 0; it < KSPLIT / BKB; ++it) {
#pragma unroll
    for (int j = 0; j < 4; ++j) {
      gld16(pA[j], lA[j]);
      gld16(pB[j], lB[j]);
      pA[j] += BKB; pB[j] += BKB;
    }
    __syncthreads();

#pragma unroll
    for (int kp = 0; kp < 2; ++kp) {
      v4i a[4], b[4];
#pragma unroll
      for (int fm = 0; fm < 4; ++fm) {
        const int row = wm + fm * 16 + lm;
        const int kgs = (kp * 4 + quad) ^ (row & 7);
        a[fm] = *(const v4i*)(As + row * BKB + kgs * 16);
      }
#pragma unroll
      for (int fn = 0; fn < 4; ++fn) {
        const int row = wn + fn * 16 + lm;
        const int kgs = (kp * 4 + quad) ^ (row & 7);
        b[fn] = *(const v4i*)(Bs + row * BKB + kgs * 16);
      }
#pragma unroll
      for (int fm = 0; fm < 4; ++fm)
#pragma unroll
        for (int fn = 0; fn < 4; ++fn)
          acc[fm][fn] = __builtin_amdgcn_mfma_i32_16x16x64_i8(a[fm], b[fn], acc[fm][fn], 0, 0, 0);
    }
    __syncthreads();
  }

  // epilogue: C/D layout (dtype-independent): col = lane&15, row = quad*4 + reg
#pragma unroll
  for (int fm = 0; fm < 4; ++fm) {
    const int row0 = bm0 + wm + fm * 16 + quad * 4;
#pragma unroll
    for (int fn = 0; fn < 4; ++fn) {
      const int col = bn0 + wn + fn * 16 + lm;
#pragma unroll
      for (int r = 0; r < 4; ++r)
        out[(size_t)(row0 + r) * OUTC + col] = f2bf((float)acc[fm][fn][r]);
    }
  }
}

// ---------------- Phase 3: reduce + dequant ----------------
// y[b,o] = M[o]*(Sdot + 127*Qc[o]) / (127*254)
__global__ __launch_bounds__(256) void reduce_kernel(
    const unsigned short* __restrict__ P, const float* __restrict__ maxrow,
    const int* __restrict__ qcsum, float* __restrict__ out) {
  const size_t nel = (size_t)BATCH * OUTC;
  const size_t base = ((size_t)blockIdx.x * 256 + threadIdx.x) * 8;
  float s[8] = {};
#pragma unroll
  for (int t = 0; t < SPLITS; ++t) {
    v8s v = *(const v8s*)(P + t * nel + base);
#pragma unroll
    for (int j = 0; j < 8; ++j) s[j] += bf2f((unsigned short)v[j]);
  }
  const int o0 = (int)(base & (OUTC - 1));
  const float inv = 1.0f / 32258.0f;   // 127*254
#pragma unroll
  for (int j = 0; j < 8; ++j) {
    const float M = maxrow[o0 + j];
    const int   Q = qcsum[o0 + j];
    s[j] = M * (s[j] + 127.0f * (float)Q) * inv;
  }
  *(float4*)(out + base)     = float4{s[0], s[1], s[2], s[3]};
  *(float4*)(out + base + 4) = float4{s[4], s[5], s[6], s[7]};
}

extern "C" void kernel_launch(void* const* d_in, const int* in_sizes, int n_in,
                              void* d_out, int out_size, void* d_ws, size_t ws_size,
                              hipStream_t stream) {
  const float* x       = (const float*)d_in[0];
  const float* coeffs  = (const float*)d_in[1];
  const float* centers = (const float*)d_in[2];
  const float* slopes  = (const float*)d_in[3];
  const float* alpha   = (const float*)d_in[4];
  const float* beta    = (const float*)d_in[5];
  float* out = (float*)d_out;

  const size_t a_bytes    = (size_t)BATCH * KDIM;                 // 32 MiB i8
  const size_t c_bytes    = (size_t)OUTC * KDIM;                  // 8 MiB i8
  const size_t stat_bytes = OUTC * sizeof(float);                 // 4 KiB
  const size_t qcs_bytes  = OUTC * sizeof(int);                   // 4 KiB
  const size_t part_bytes = (size_t)SPLITS * BATCH * OUTC * 2;    // 33.5 MiB bf16
  if (ws_size < a_bytes + c_bytes + stat_bytes + qcs_bytes + part_bytes) return;

  char*  Ai8    = (char*)d_ws;
  char*  Ci8    = Ai8 + a_bytes;
  float* maxrow = (float*)(Ci8 + c_bytes);
  int*   qcsum  = (int*)((char*)maxrow + stat_bytes);
  unsigned short* parts = (unsigned short*)((char*)qcsum + qcs_bytes);

  prep_kernel<<<PREP_BLOCKS, 256, 0, stream>>>(
      x, (const float4*)coeffs, centers, slopes, alpha, beta,
      Ai8, (int*)Ci8, maxrow, qcsum);

  gemm_kernel<<<(OUTC / BN) * (BATCH / BM) * SPLITS, 256, 0, stream>>>(
      Ai8, Ci8, parts);

  reduce_kernel<<<(int)((size_t)BATCH * OUTC / 8 / 256), 256, 0, stream>>>(
      parts, maxrow, qcsum, out);
}

// Round 8
// 155.248 us; speedup vs baseline: 1.6560x; 1.0607x over previous
//
#include <hip/hip_runtime.h>
#include <hip/hip_bf16.h>
#include <cstdint>
#include <cstddef>

#define BATCH 4096
#define INC   1024
#define OUTC  1024
#define NB    8
#define KDIM  (INC * NB)   // 8192 (elements == bytes in i8)

// GEMM tile: 128x128 block, BK=128 i8, 4 waves of 64x64 (4x4 frags of 16x16x64 i8)
#define BM 128
#define BN 128
#define BKB 128            // k-bytes per iter
#define SPLITS 4
#define KSPLIT (KDIM / SPLITS)   // 2048 -> 16 K-iters per block
#define GRID_BLOCKS ((OUTC / BN) * (BATCH / BM) * SPLITS)   // 1024

// prep dispatch partition: expand | fused rowmax+quant (one block per coeff row)
#define EXPAND_BLOCKS  ((BATCH * INC) / 256)   // 16384
#define QUANT_BLOCKS   OUTC                    // 1024
#define PREP_BLOCKS    (EXPAND_BLOCKS + QUANT_BLOCKS)

typedef int   v4i __attribute__((ext_vector_type(4)));
typedef char  v8c __attribute__((ext_vector_type(8)));
typedef short v8s __attribute__((ext_vector_type(8)));

__device__ __forceinline__ unsigned short f2bf(float f) {
  union { float f; unsigned u; } v; v.f = f;
  unsigned r = v.u + 0x7fffu + ((v.u >> 16) & 1u);  // round-to-nearest-even
  return (unsigned short)(r >> 16);
}
__device__ __forceinline__ float bf2f(unsigned short h) {
  union { unsigned u; float f; } v; v.u = ((unsigned)h) << 16; return v.f;
}

// async 16B global -> LDS (DMA; LDS dest = wave-uniform base + lane*16)
__device__ __forceinline__ void gld16(const char* g, char* l) {
  __builtin_amdgcn_global_load_lds(
      (const __attribute__((address_space(1))) unsigned int*)g,
      (__attribute__((address_space(3))) unsigned int*)l, 16, 0, 0);
}

// ---------------- Phase 1 (fused dispatch): expand basis | rowmax+quantize coeffs -------
// expand: basis_m = sigmoid(2*s*(u-c_m)); equispaced centers + uniform slope ->
//   e_m = e0*R^m (2 exp2 total). Affine quant qa = rint(basis*254-127).
// quant: one block per coeff row; row (32KB) held in registers across max-reduce,
//   then quantized: qc = rint(c*127/M). qcsum computed in-block (no atomics/memset).
__global__ __launch_bounds__(256) void prep_kernel(
    const float* __restrict__ x, const float4* __restrict__ coeffs4,
    const float* __restrict__ centers, const float* __restrict__ slopes,
    const float* __restrict__ alpha, const float* __restrict__ beta,
    char* __restrict__ Ai8, int* __restrict__ Ci8i,
    float* __restrict__ maxrow, int* __restrict__ qcsum) {
  const int blk = blockIdx.x;
  const int tid = threadIdx.x;
  if (blk < EXPAND_BLOCKS) {
    const int idx = blk * 256 + tid;          // (b,i) pair
    const int i = idx & (INC - 1);
    const float u = alpha[i] * x[idx] + beta[i];
    const float s0 = slopes[i * NB];
    const float c0 = centers[i * NB];
    const float c1 = centers[i * NB + 1];
    const float L2E2 = 2.8853900817779268f;   // 2*log2(e)
    const float a2 = L2E2 * s0;
    float e = __builtin_amdgcn_exp2f(a2 * (c0 - u));   // inf -> rcp -> 0: correct limit
    const float R = __builtin_amdgcn_exp2f(a2 * (c1 - c0));
    v8c q;
#pragma unroll
    for (int m = 0; m < 8; ++m) {
      float basis = __builtin_amdgcn_rcpf(1.0f + e);
      q[m] = (char)(int)rintf(basis * 254.0f - 127.0f);
      e *= R;
    }
    *(v8c*)(Ai8 + (size_t)idx * 8) = q;   // 8B coalesced store
  } else {
    const int o = blk - EXPAND_BLOCKS;
    const float4* row = coeffs4 + (size_t)o * (KDIM / 4);
    float4 v[8];
    float m = 0.0f;
#pragma unroll
    for (int j = 0; j < 8; ++j) {
      v[j] = row[tid + 256 * j];
      m = fmaxf(m, fmaxf(fmaxf(fabsf(v[j].x), fabsf(v[j].y)),
                         fmaxf(fabsf(v[j].z), fabsf(v[j].w))));
    }
#pragma unroll
    for (int off = 32; off; off >>= 1) m = fmaxf(m, __shfl_xor(m, off));
    __shared__ float wm[4];
    __shared__ int   wq[4];
    if ((tid & 63) == 0) wm[tid >> 6] = m;
    __syncthreads();
    const float M = fmaxf(fmaxf(fmaxf(wm[0], wm[1]), fmaxf(wm[2], wm[3])), 1e-30f);
    const float s = 127.0f / M;
    int qs = 0;
#pragma unroll
    for (int j = 0; j < 8; ++j) {
      int q0 = (int)rintf(v[j].x * s), q1 = (int)rintf(v[j].y * s);
      int q2 = (int)rintf(v[j].z * s), q3 = (int)rintf(v[j].w * s);
      Ci8i[(size_t)o * (KDIM / 4) + tid + 256 * j] =
          (q0 & 0xFF) | ((q1 & 0xFF) << 8) | ((q2 & 0xFF) << 16) | ((q3 & 0xFF) << 24);
      qs += q0 + q1 + q2 + q3;
    }
#pragma unroll
    for (int off = 32; off; off >>= 1) qs += __shfl_xor(qs, off);
    if ((tid & 63) == 0) wq[tid >> 6] = qs;
    __syncthreads();
    if (tid == 0) { maxrow[o] = M; qcsum[o] = wq[0] + wq[1] + wq[2] + wq[3]; }
  }
}

// ---------------- Phase 2: i8 16x16x64 MFMA GEMM, split-K=4 -> bf16 partials ------------
// y_dot[m,n] = sum_k qa[m,k]*qc[n,k].  LDS XOR-swizzled in 16B k-groups: slot (row,g)
// holds global group g^(row&7); fragment reads kgs=(kp*4+quad)^(row&7) -> <=2-way (free).
// XCD-aware remap: HW dispatches block i to XCD i&7; remap so each XCD owns 128
// CONSECUTIVE logical blocks (= 2 supertiles of 64; 4MB working set fits its 4MB L2),
// killing the ~3.4x cross-XCD L2 duplication seen as FETCH 135MB vs 40MB working set.
__global__ __launch_bounds__(256) void gemm_kernel(
    const char* __restrict__ A, const char* __restrict__ C,
    unsigned short* __restrict__ partials) {
  __shared__ char As[BM * BKB];   // 16 KiB
  __shared__ char Bs[BN * BKB];   // 16 KiB

  // XCD-aware: logical = (phys&7)*128 + phys>>3
  const int id = (blockIdx.x & 7) * (GRID_BLOCKS / 8) + (blockIdx.x >> 3);
  // logical decode: 256 blocks per z-plane; 8x8 supertiles consecutive
  const int z  = id >> 8;
  const int p  = id & 255;
  const int st = p >> 6;
  const int q  = p & 63;
  const int bx = q & 7;
  const int by = st * 8 + (q >> 3);
  const int bn0 = bx * BN;
  const int bm0 = by * BM;

  const int tid  = threadIdx.x;
  const int wave = tid >> 6;
  const int lane = tid & 63;
  const int quad = lane >> 4;
  const int lm   = lane & 15;
  const int wm = (wave & 1) * 64;
  const int wn = (wave >> 1) * 64;
  const int kt0 = z * KSPLIT;
  unsigned short* out = partials + (size_t)z * BATCH * OUTC;

  // staging decode: lane covers LDS slot (row = rb + (lane>>3), group lane&7);
  // fetches global 16B-group kg = (lane&7) ^ row
  const int r_in = lane >> 3;
  const int kg   = (lane & 7) ^ r_in;

  const char* pA[4];
  const char* pB[4];
  char* lA[4];
  char* lB[4];
#pragma unroll
  for (int j = 0; j < 4; ++j) {
    const int rb = wave * 32 + j * 8;
    pA[j] = A + (size_t)(bm0 + rb + r_in) * KDIM + kt0 + kg * 16;
    pB[j] = C + (size_t)(bn0 + rb + r_in) * KDIM + kt0 + kg * 16;
    lA[j] = As + rb * BKB;
    lB[j] = Bs + rb * BKB;
  }

  v4i acc[4][4] = {};

  for (int it = 0; it < KSPLIT / BKB; ++it) {
#pragma unroll
    for (int j = 0; j < 4; ++j) {
      gld16(pA[j], lA[j]);
      gld16(pB[j], lB[j]);
      pA[j] += BKB; pB[j] += BKB;
    }
    __syncthreads();

#pragma unroll
    for (int kp = 0; kp < 2; ++kp) {
      v4i a[4], b[4];
#pragma unroll
      for (int fm = 0; fm < 4; ++fm) {
        const int row = wm + fm * 16 + lm;
        const int kgs = (kp * 4 + quad) ^ (row & 7);
        a[fm] = *(const v4i*)(As + row * BKB + kgs * 16);
      }
#pragma unroll
      for (int fn = 0; fn < 4; ++fn) {
        const int row = wn + fn * 16 + lm;
        const int kgs = (kp * 4 + quad) ^ (row & 7);
        b[fn] = *(const v4i*)(Bs + row * BKB + kgs * 16);
      }
#pragma unroll
      for (int fm = 0; fm < 4; ++fm)
#pragma unroll
        for (int fn = 0; fn < 4; ++fn)
          acc[fm][fn] = __builtin_amdgcn_mfma_i32_16x16x64_i8(a[fm], b[fn], acc[fm][fn], 0, 0, 0);
    }
    __syncthreads();
  }

  // epilogue: C/D layout (dtype-independent): col = lane&15, row = quad*4 + reg
#pragma unroll
  for (int fm = 0; fm < 4; ++fm) {
    const int row0 = bm0 + wm + fm * 16 + quad * 4;
#pragma unroll
    for (int fn = 0; fn < 4; ++fn) {
      const int col = bn0 + wn + fn * 16 + lm;
#pragma unroll
      for (int r = 0; r < 4; ++r)
        out[(size_t)(row0 + r) * OUTC + col] = f2bf((float)acc[fm][fn][r]);
    }
  }
}

// ---------------- Phase 3: reduce + dequant ----------------
// y[b,o] = M[o]*(Sdot + 127*Qc[o]) / (127*254)
__global__ __launch_bounds__(256) void reduce_kernel(
    const unsigned short* __restrict__ P, const float* __restrict__ maxrow,
    const int* __restrict__ qcsum, float* __restrict__ out) {
  const size_t nel = (size_t)BATCH * OUTC;
  const size_t base = ((size_t)blockIdx.x * 256 + threadIdx.x) * 8;
  float s[8] = {};
#pragma unroll
  for (int t = 0; t < SPLITS; ++t) {
    v8s v = *(const v8s*)(P + t * nel + base);
#pragma unroll
    for (int j = 0; j < 8; ++j) s[j] += bf2f((unsigned short)v[j]);
  }
  const int o0 = (int)(base & (OUTC - 1));
  const float inv = 1.0f / 32258.0f;   // 127*254
#pragma unroll
  for (int j = 0; j < 8; ++j) {
    const float M = maxrow[o0 + j];
    const int   Q = qcsum[o0 + j];
    s[j] = M * (s[j] + 127.0f * (float)Q) * inv;
  }
  *(float4*)(out + base)     = float4{s[0], s[1], s[2], s[3]};
  *(float4*)(out + base + 4) = float4{s[4], s[5], s[6], s[7]};
}

extern "C" void kernel_launch(void* const* d_in, const int* in_sizes, int n_in,
                              void* d_out, int out_size, void* d_ws, size_t ws_size,
                              hipStream_t stream) {
  const float* x       = (const float*)d_in[0];
  const float* coeffs  = (const float*)d_in[1];
  const float* centers = (const float*)d_in[2];
  const float* slopes  = (const float*)d_in[3];
  const float* alpha   = (const float*)d_in[4];
  const float* beta    = (const float*)d_in[5];
  float* out = (float*)d_out;

  const size_t a_bytes    = (size_t)BATCH * KDIM;                 // 32 MiB i8
  const size_t c_bytes    = (size_t)OUTC * KDIM;                  // 8 MiB i8
  const size_t stat_bytes = OUTC * sizeof(float);                 // 4 KiB
  const size_t qcs_bytes  = OUTC * sizeof(int);                   // 4 KiB
  const size_t part_bytes = (size_t)SPLITS * BATCH * OUTC * 2;    // 33.5 MiB bf16
  if (ws_size < a_bytes + c_bytes + stat_bytes + qcs_bytes + part_bytes) return;

  char*  Ai8    = (char*)d_ws;
  char*  Ci8    = Ai8 + a_bytes;
  float* maxrow = (float*)(Ci8 + c_bytes);
  int*   qcsum  = (int*)((char*)maxrow + stat_bytes);
  unsigned short* parts = (unsigned short*)((char*)qcsum + qcs_bytes);

  prep_kernel<<<PREP_BLOCKS, 256, 0, stream>>>(
      x, (const float4*)coeffs, centers, slopes, alpha, beta,
      Ai8, (int*)Ci8, maxrow, qcsum);

  gemm_kernel<<<GRID_BLOCKS, 256, 0, stream>>>(Ai8, Ci8, parts);

  reduce_kernel<<<(int)((size_t)BATCH * OUTC / 8 / 256), 256, 0, stream>>>(
      parts, maxrow, qcsum, out);
}

// Round 9
// 152.839 us; speedup vs baseline: 1.6821x; 1.0158x over previous
//
#include <hip/hip_runtime.h>
#include <hip/hip_bf16.h>
#include <cstdint>
#include <cstddef>

#define BATCH 4096
#define INC   1024
#define OUTC  1024
#define NB    8
#define KDIM  (INC * NB)   // 8192 (elements == bytes in i8)

// GEMM tile: 128x128 block, BK=128 i8, 4 waves of 64x64 (4x4 frags of 16x16x64 i8)
#define BM 128
#define BN 128
#define BKB 128            // k-bytes per iter
#define SPLITS 3           // grid 768 = exactly 3 blocks/CU resident -> one clean round
#define GRID_BLOCKS ((OUTC / BN) * (BATCH / BM) * SPLITS)   // 768
// K-iters per z: 22,21,21 (sum 64); kt0 bytes: 0, 2816, 5504

// prep dispatch partition: expand | fused rowmax+quant (one block per coeff row)
#define EXPAND_BLOCKS  ((BATCH * INC) / 256)   // 16384
#define QUANT_BLOCKS   OUTC                    // 1024
#define PREP_BLOCKS    (EXPAND_BLOCKS + QUANT_BLOCKS)

typedef int   v4i __attribute__((ext_vector_type(4)));
typedef char  v8c __attribute__((ext_vector_type(8)));
typedef short v8s __attribute__((ext_vector_type(8)));

__device__ __forceinline__ unsigned short f2bf(float f) {
  union { float f; unsigned u; } v; v.f = f;
  unsigned r = v.u + 0x7fffu + ((v.u >> 16) & 1u);  // round-to-nearest-even
  return (unsigned short)(r >> 16);
}
__device__ __forceinline__ float bf2f(unsigned short h) {
  union { unsigned u; float f; } v; v.u = ((unsigned)h) << 16; return v.f;
}

// async 16B global -> LDS (DMA; LDS dest = wave-uniform base + lane*16)
__device__ __forceinline__ void gld16(const char* g, char* l) {
  __builtin_amdgcn_global_load_lds(
      (const __attribute__((address_space(1))) unsigned int*)g,
      (__attribute__((address_space(3))) unsigned int*)l, 16, 0, 0);
}

// ---------------- Phase 1 (fused dispatch): expand basis | rowmax+quantize coeffs -------
// expand: basis_m = sigmoid(2*s*(u-c_m)); equispaced centers + uniform slope ->
//   e_m = e0*R^m (2 exp2 total). Affine quant qa = rint(basis*254-127).
// quant: one block per coeff row; row (32KB) held in registers across max-reduce,
//   then quantized: qc = rint(c*127/M). qcsum computed in-block (no atomics/memset).
__global__ __launch_bounds__(256) void prep_kernel(
    const float* __restrict__ x, const float4* __restrict__ coeffs4,
    const float* __restrict__ centers, const float* __restrict__ slopes,
    const float* __restrict__ alpha, const float* __restrict__ beta,
    char* __restrict__ Ai8, int* __restrict__ Ci8i,
    float* __restrict__ maxrow, int* __restrict__ qcsum) {
  const int blk = blockIdx.x;
  const int tid = threadIdx.x;
  if (blk < EXPAND_BLOCKS) {
    const int idx = blk * 256 + tid;          // (b,i) pair
    const int i = idx & (INC - 1);
    const float u = alpha[i] * x[idx] + beta[i];
    const float s0 = slopes[i * NB];
    const float c0 = centers[i * NB];
    const float c1 = centers[i * NB + 1];
    const float L2E2 = 2.8853900817779268f;   // 2*log2(e)
    const float a2 = L2E2 * s0;
    float e = __builtin_amdgcn_exp2f(a2 * (c0 - u));   // inf -> rcp -> 0: correct limit
    const float R = __builtin_amdgcn_exp2f(a2 * (c1 - c0));
    v8c q;
#pragma unroll
    for (int m = 0; m < 8; ++m) {
      float basis = __builtin_amdgcn_rcpf(1.0f + e);
      q[m] = (char)(int)rintf(basis * 254.0f - 127.0f);
      e *= R;
    }
    *(v8c*)(Ai8 + (size_t)idx * 8) = q;   // 8B coalesced store
  } else {
    const int o = blk - EXPAND_BLOCKS;
    const float4* row = coeffs4 + (size_t)o * (KDIM / 4);
    float4 v[8];
    float m = 0.0f;
#pragma unroll
    for (int j = 0; j < 8; ++j) {
      v[j] = row[tid + 256 * j];
      m = fmaxf(m, fmaxf(fmaxf(fabsf(v[j].x), fabsf(v[j].y)),
                         fmaxf(fabsf(v[j].z), fabsf(v[j].w))));
    }
#pragma unroll
    for (int off = 32; off; off >>= 1) m = fmaxf(m, __shfl_xor(m, off));
    __shared__ float wm[4];
    __shared__ int   wq[4];
    if ((tid & 63) == 0) wm[tid >> 6] = m;
    __syncthreads();
    const float M = fmaxf(fmaxf(fmaxf(wm[0], wm[1]), fmaxf(wm[2], wm[3])), 1e-30f);
    const float s = 127.0f / M;
    int qs = 0;
#pragma unroll
    for (int j = 0; j < 8; ++j) {
      int q0 = (int)rintf(v[j].x * s), q1 = (int)rintf(v[j].y * s);
      int q2 = (int)rintf(v[j].z * s), q3 = (int)rintf(v[j].w * s);
      Ci8i[(size_t)o * (KDIM / 4) + tid + 256 * j] =
          (q0 & 0xFF) | ((q1 & 0xFF) << 8) | ((q2 & 0xFF) << 16) | ((q3 & 0xFF) << 24);
      qs += q0 + q1 + q2 + q3;
    }
#pragma unroll
    for (int off = 32; off; off >>= 1) qs += __shfl_xor(qs, off);
    if ((tid & 63) == 0) wq[tid >> 6] = qs;
    __syncthreads();
    if (tid == 0) { maxrow[o] = M; qcsum[o] = wq[0] + wq[1] + wq[2] + wq[3]; }
  }
}

// ---------------- Phase 2: i8 16x16x64 MFMA GEMM, split-K=3 -> bf16 partials ------------
// y_dot[m,n] = sum_k qa[m,k]*qc[n,k].  LDS XOR-swizzled in 16B k-groups: slot (row,g)
// holds global group g^(row&7); fragment reads kgs=(kp*4+quad)^(row&7) -> <=2-way (free).
// XCD-aware remap: each XCD owns 96 consecutive logical blocks (supertile locality in
// its private L2; FETCH == working set, verified R8). Grid 768 = 3 blocks/CU resident
// (160 unified regs/wave => 3 waves/SIMD) -> ONE clean dispatch round, no tail.
__global__ __launch_bounds__(256, 3) void gemm_kernel(
    const char* __restrict__ A, const char* __restrict__ C,
    unsigned short* __restrict__ partials) {
  __shared__ char As[BM * BKB];   // 16 KiB
  __shared__ char Bs[BN * BKB];   // 16 KiB

  // XCD-aware: logical = (phys&7)*96 + phys>>3
  const int id = (blockIdx.x & 7) * (GRID_BLOCKS / 8) + (blockIdx.x >> 3);
  // logical decode: 256 blocks per z-plane; 8x8 supertiles consecutive
  const int z  = id >> 8;
  const int p  = id & 255;
  const int st = p >> 6;
  const int q  = p & 63;
  const int bx = q & 7;
  const int by = st * 8 + (q >> 3);
  const int bn0 = bx * BN;
  const int bm0 = by * BM;

  // uneven split-K: iters 22,21,21; kt0 bytes 0,2816,5504
  const int iters = (z == 0) ? 22 : 21;
  const int kt0   = (z == 0) ? 0 : (2816 + 2688 * (z - 1));

  const int tid  = threadIdx.x;
  const int wave = tid >> 6;
  const int lane = tid & 63;
  const int quad = lane >> 4;
  const int lm   = lane & 15;
  const int wm = (wave & 1) * 64;
  const int wn = (wave >> 1) * 64;
  unsigned short* out = partials + (size_t)z * BATCH * OUTC;

  // staging decode: lane covers LDS slot (row = rb + (lane>>3), group lane&7);
  // fetches global 16B-group kg = (lane&7) ^ row
  const int r_in = lane >> 3;
  const int kg   = (lane & 7) ^ r_in;

  const char* pA[4];
  const char* pB[4];
  char* lA[4];
  char* lB[4];
#pragma unroll
  for (int j = 0; j < 4; ++j) {
    const int rb = wave * 32 + j * 8;
    pA[j] = A + (size_t)(bm0 + rb + r_in) * KDIM + kt0 + kg * 16;
    pB[j] = C + (size_t)(bn0 + rb + r_in) * KDIM + kt0 + kg * 16;
    lA[j] = As + rb * BKB;
    lB[j] = Bs + rb * BKB;
  }

  v4i acc[4][4] = {};

  for (int it = 0; it < iters; ++it) {
#pragma unroll
    for (int j = 0; j < 4; ++j) {
      gld16(pA[j], lA[j]);
      gld16(pB[j], lB[j]);
      pA[j] += BKB; pB[j] += BKB;
    }
    __syncthreads();

#pragma unroll
    for (int kp = 0; kp < 2; ++kp) {
      v4i a[4], b[4];
#pragma unroll
      for (int fm = 0; fm < 4; ++fm) {
        const int row = wm + fm * 16 + lm;
        const int kgs = (kp * 4 + quad) ^ (row & 7);
        a[fm] = *(const v4i*)(As + row * BKB + kgs * 16);
      }
#pragma unroll
      for (int fn = 0; fn < 4; ++fn) {
        const int row = wn + fn * 16 + lm;
        const int kgs = (kp * 4 + quad) ^ (row & 7);
        b[fn] = *(const v4i*)(Bs + row * BKB + kgs * 16);
      }
#pragma unroll
      for (int fm = 0; fm < 4; ++fm)
#pragma unroll
        for (int fn = 0; fn < 4; ++fn)
          acc[fm][fn] = __builtin_amdgcn_mfma_i32_16x16x64_i8(a[fm], b[fn], acc[fm][fn], 0, 0, 0);
    }
    __syncthreads();
  }

  // epilogue: C/D layout (dtype-independent): col = lane&15, row = quad*4 + reg
#pragma unroll
  for (int fm = 0; fm < 4; ++fm) {
    const int row0 = bm0 + wm + fm * 16 + quad * 4;
#pragma unroll
    for (int fn = 0; fn < 4; ++fn) {
      const int col = bn0 + wn + fn * 16 + lm;
#pragma unroll
      for (int r = 0; r < 4; ++r)
        out[(size_t)(row0 + r) * OUTC + col] = f2bf((float)acc[fm][fn][r]);
    }
  }
}

// ---------------- Phase 3: reduce + dequant ----------------
// y[b,o] = M[o]*(Sdot + 127*Qc[o]) / (127*254)
__global__ __launch_bounds__(256) void reduce_kernel(
    const unsigned short* __restrict__ P, const float* __restrict__ maxrow,
    const int* __restrict__ qcsum, float* __restrict__ out) {
  const size_t nel = (size_t)BATCH * OUTC;
  const size_t base = ((size_t)blockIdx.x * 256 + threadIdx.x) * 8;
  float s[8] = {};
#pragma unroll
  for (int t = 0; t < SPLITS; ++t) {
    v8s v = *(const v8s*)(P + t * nel + base);
#pragma unroll
    for (int j = 0; j < 8; ++j) s[j] += bf2f((unsigned short)v[j]);
  }
  const int o0 = (int)(base & (OUTC - 1));
  const float inv = 1.0f / 32258.0f;   // 127*254
#pragma unroll
  for (int j = 0; j < 8; ++j) {
    const float M = maxrow[o0 + j];
    const int   Q = qcsum[o0 + j];
    s[j] = M * (s[j] + 127.0f * (float)Q) * inv;
  }
  *(float4*)(out + base)     = float4{s[0], s[1], s[2], s[3]};
  *(float4*)(out + base + 4) = float4{s[4], s[5], s[6], s[7]};
}

extern "C" void kernel_launch(void* const* d_in, const int* in_sizes, int n_in,
                              void* d_out, int out_size, void* d_ws, size_t ws_size,
                              hipStream_t stream) {
  const float* x       = (const float*)d_in[0];
  const float* coeffs  = (const float*)d_in[1];
  const float* centers = (const float*)d_in[2];
  const float* slopes  = (const float*)d_in[3];
  const float* alpha   = (const float*)d_in[4];
  const float* beta    = (const float*)d_in[5];
  float* out = (float*)d_out;

  const size_t a_bytes    = (size_t)BATCH * KDIM;                 // 32 MiB i8
  const size_t c_bytes    = (size_t)OUTC * KDIM;                  // 8 MiB i8
  const size_t stat_bytes = OUTC * sizeof(float);                 // 4 KiB
  const size_t qcs_bytes  = OUTC * sizeof(int);                   // 4 KiB
  const size_t part_bytes = (size_t)SPLITS * BATCH * OUTC * 2;    // 25 MiB bf16
  if (ws_size < a_bytes + c_bytes + stat_bytes + qcs_bytes + part_bytes) return;

  char*  Ai8    = (char*)d_ws;
  char*  Ci8    = Ai8 + a_bytes;
  float* maxrow = (float*)(Ci8 + c_bytes);
  int*   qcsum  = (int*)((char*)maxrow + stat_bytes);
  unsigned short* parts = (unsigned short*)((char*)qcsum + qcs_bytes);

  prep_kernel<<<PREP_BLOCKS, 256, 0, stream>>>(
      x, (const float4*)coeffs, centers, slopes, alpha, beta,
      Ai8, (int*)Ci8, maxrow, qcsum);

  gemm_kernel<<<GRID_BLOCKS, 256, 0, stream>>>(Ai8, Ci8, parts);

  reduce_kernel<<<(int)((size_t)BATCH * OUTC / 8 / 256), 256, 0, stream>>>(
      parts, maxrow, qcsum, out);
}